// Round 1
// baseline (262.747 us; speedup 1.0000x reference)
//
#include <hip/hip_runtime.h>

// Problem geometry (fixed by setup_inputs): x is (16, 1, 1536, 1536) fp32,
// kernel_size = 3. Non-overlapping 3x3 max-pool + unpool: keep only the
// first-argmax value in each 3x3 block (row-major in-block order), zero rest.
//
// One thread handles 4 consecutive 3x3 blocks along W -> its row slice is
// 12 floats = 3x float4, 48B-aligned. Fully vectorized 16B loads/stores.

#define IMG_H 1536
#define IMG_W 1536
#define N_IMG 16          // B*C = 16*1
#define HK    512         // H/3
#define WK4   128         // (W/3)/4  groups of 4 blocks

__global__ __launch_bounds__(256) void pool_nms_kernel(const float* __restrict__ x,
                                                       float* __restrict__ out) {
    const int tid = blockIdx.x * 256 + threadIdx.x;
    const int bw4 = tid & (WK4 - 1);   // % 128
    const int t2  = tid >> 7;
    const int bh  = t2 & (HK - 1);     // % 512
    const int n   = t2 >> 9;

    const size_t base = (size_t)n * (IMG_H * (size_t)IMG_W)
                      + (size_t)(bh * 3) * IMG_W
                      + (size_t)bw4 * 12;

    // Load 3 rows x 12 floats (3x float4 each)
    float row[3][12];
#pragma unroll
    for (int r = 0; r < 3; ++r) {
        const float* p = x + base + (size_t)r * IMG_W;
#pragma unroll
        for (int j = 0; j < 3; ++j) {
            float4 t = *(const float4*)(p + j * 4);
            row[r][j * 4 + 0] = t.x;
            row[r][j * 4 + 1] = t.y;
            row[r][j * 4 + 2] = t.z;
            row[r][j * 4 + 3] = t.w;
        }
    }

    // Per sub-block argmax (first max wins: strict > in row-major order),
    // then predicated zeroing. All indices compile-time after unroll.
    float o[3][12];
#pragma unroll
    for (int s = 0; s < 4; ++s) {
        const int c0 = s * 3;
        float best = row[0][c0];
        int bi = 0;
#pragma unroll
        for (int r = 0; r < 3; ++r) {
#pragma unroll
            for (int c = 0; c < 3; ++c) {
                const float vv = row[r][c0 + c];
                if (vv > best) { best = vv; bi = r * 3 + c; }
            }
        }
#pragma unroll
        for (int r = 0; r < 3; ++r) {
#pragma unroll
            for (int c = 0; c < 3; ++c) {
                o[r][c0 + c] = ((r * 3 + c) == bi) ? row[r][c0 + c] : 0.0f;
            }
        }
    }

    // Store 3 rows x 3x float4
#pragma unroll
    for (int r = 0; r < 3; ++r) {
        float* p = out + base + (size_t)r * IMG_W;
#pragma unroll
        for (int j = 0; j < 3; ++j) {
            *(float4*)(p + j * 4) = make_float4(o[r][j * 4 + 0], o[r][j * 4 + 1],
                                                o[r][j * 4 + 2], o[r][j * 4 + 3]);
        }
    }
}

extern "C" void kernel_launch(void* const* d_in, const int* in_sizes, int n_in,
                              void* d_out, int out_size, void* d_ws, size_t ws_size,
                              hipStream_t stream) {
    const float* x = (const float*)d_in[0];
    float* out = (float*)d_out;
    // total threads = 16 * 512 * 128 = 1,048,576 -> 4096 workgroups of 256
    const int n_threads = N_IMG * HK * WK4;
    pool_nms_kernel<<<n_threads / 256, 256, 0, stream>>>(x, out);
}

// Round 2
// 257.535 us; speedup vs baseline: 1.0202x; 1.0202x over previous
//
#include <hip/hip_runtime.h>

// x: (16,1,1536,1536) fp32, kernel_size=3. Keep only first-argmax value per
// non-overlapping 3x3 block, zero the rest.
//
// Round-1 lesson: per-lane 48-B chunks made every global load/store a
// stride-48 scatter (~1.15 TB/s). Fix: LDS-stage a 6x1536 tile so all global
// traffic is consecutive-lane float4 (perfectly coalesced); the strided
// block-gather happens in LDS instead.

#define IMG_H 1536
#define IMG_W 1536
#define N_IMG 16
#define TILE_ROWS 6                       // 2 block-rows
#define TILE_F (TILE_ROWS * IMG_W)        // 9216 floats = 36 KB
#define TILE_V (TILE_F / 4)               // 2304 float4
#define V_PER_T (TILE_V / 256)            // 9 float4 per thread per phase
#define TILES_PER_IMG (IMG_H / TILE_ROWS) // 256

__global__ __launch_bounds__(256) void pool_nms_kernel(const float* __restrict__ x,
                                                       float* __restrict__ out) {
    __shared__ float lds[TILE_F];

    const int wg = blockIdx.x;
    const int n  = wg >> 8;                 // / TILES_PER_IMG
    const int tr = wg & (TILES_PER_IMG - 1);
    const size_t base = (size_t)n * (IMG_H * (size_t)IMG_W)
                      + (size_t)(tr * TILE_ROWS) * IMG_W;
    const int t = threadIdx.x;

    // Phase 1: coalesced global -> LDS (lane i gets float4 #(t + k*256))
    const float4* xin = (const float4*)(x + base);
#pragma unroll
    for (int k = 0; k < V_PER_T; ++k) {
        const int v = t + k * 256;
        ((float4*)lds)[v] = xin[v];
    }
    __syncthreads();

    // Phase 2: each thread owns 4 consecutive 3x3 blocks in one block-row.
    const int br = t >> 7;        // 0..1  block-row within tile
    const int g  = t & 127;       // group of 4 blocks along W
    float row[3][12];
#pragma unroll
    for (int r = 0; r < 3; ++r) {
        const float* p = lds + (br * 3 + r) * IMG_W + g * 12;
#pragma unroll
        for (int j = 0; j < 3; ++j) {
            float4 v4 = *(const float4*)(p + j * 4);
            row[r][j * 4 + 0] = v4.x;
            row[r][j * 4 + 1] = v4.y;
            row[r][j * 4 + 2] = v4.z;
            row[r][j * 4 + 3] = v4.w;
        }
    }

    float o[3][12];
#pragma unroll
    for (int s = 0; s < 4; ++s) {
        const int c0 = s * 3;
        float best = row[0][c0];
        int bi = 0;
#pragma unroll
        for (int r = 0; r < 3; ++r) {
#pragma unroll
            for (int c = 0; c < 3; ++c) {
                const float vv = row[r][c0 + c];
                if (vv > best) { best = vv; bi = r * 3 + c; }
            }
        }
#pragma unroll
        for (int r = 0; r < 3; ++r) {
#pragma unroll
            for (int c = 0; c < 3; ++c) {
                o[r][c0 + c] = ((r * 3 + c) == bi) ? row[r][c0 + c] : 0.0f;
            }
        }
    }

    // write back in place (cells are exclusive to this thread)
#pragma unroll
    for (int r = 0; r < 3; ++r) {
        float* p = lds + (br * 3 + r) * IMG_W + g * 12;
#pragma unroll
        for (int j = 0; j < 3; ++j) {
            *(float4*)(p + j * 4) = make_float4(o[r][j * 4 + 0], o[r][j * 4 + 1],
                                                o[r][j * 4 + 2], o[r][j * 4 + 3]);
        }
    }
    __syncthreads();

    // Phase 3: coalesced LDS -> global
    float4* po = (float4*)(out + base);
#pragma unroll
    for (int k = 0; k < V_PER_T; ++k) {
        const int v = t + k * 256;
        po[v] = ((const float4*)lds)[v];
    }
}

extern "C" void kernel_launch(void* const* d_in, const int* in_sizes, int n_in,
                              void* d_out, int out_size, void* d_ws, size_t ws_size,
                              hipStream_t stream) {
    const float* x = (const float*)d_in[0];
    float* out = (float*)d_out;
    const int n_wg = N_IMG * TILES_PER_IMG;   // 4096
    pool_nms_kernel<<<n_wg, 256, 0, stream>>>(x, out);
}